// Round 12
// baseline (80.474 us; speedup 1.0000x reference)
//
#include <hip/hip_runtime.h>

typedef unsigned long long u64;
typedef unsigned short u16;

#define HH 384
#define WW 384
#define BB 8
#define CC 3
#define NMASK (BB*CC)        // 24
#define PLANE (HH*WW)        // 147456
#define NW 6                 // 384 rows = 6 x 64-bit words
#define ROWS_PG 4            // 4 | 64 -> a row group never spans bitmask words
#define GROUPS 96            // 384/4 -> 768 blocks = 3/CU even
#define CHUNK 4              // fallback ring radii per batch
#define INF_F 1.0e6f

// ---------------------------------------------------------------------------
// Algebra: only the 3 per-class bg EDT fields d_c(q)=dist(q,{t==c}) are
// computed. fg_c(q)=dist(q,{t!=c}) = 0 where t(q)!=c, else min of the other
// two d's (dist-to-union = min of dists; bit-exact, sqrt monotone).
// loss = sum_m S_bg/max_bg - S_fg/max_fg  (divide-after-sum; ~1e-7 rel)
// mask non-empty <=> max_bg <= 1000 (real EDT max < 542; empty-set >= 1e6)
//
// Row-EDT: aligned 12-float window [basek, basek+12) ⊇ [j-4, j+4]∩[0,WW) of
// candidates fl((k-j)^2 + g2[k]) — every one is an exact reference candidate
// (diff^2 exact fp32 int, fmaf rounds = fl(fl(diff^2)+g2)). If mn <= 25, all
// |k-j| >= 5 candidates are >= 25 >= mn (fp32 add of nonnegatives >= each
// operand under RN) -> done; else (P ~ (2/3)^60 ~ 0, but handled) serial
// chunked fallback from r=5 with clamped indices (clamped entries duplicate
// true candidates with larger radius term — safe, min unchanged).
//
// Latency structure (R12): all global loads (18 bm words + 12 logits) issued
// in one batch at kernel start; softmax computed pre-barrier (overlaps the
// phase-A LDS writes); window min split into two parallel dependency chains.
//
// Wave reduction: DPP (row_shr 1/2/4/8 + row_bcast 15/31), identity 0 (all
// values >= 0), result in lane 63 — VALU pipe, zero LDS-crossbar traffic.
//
// ws layout:
//   u64   bm[BB][CC][NW][WW]        column seed bitmasks (442368 B)
//   float out12[NMASK][4][GROUPS]   per-(b,c): {Sbg,Sfg,Mbg,Mfg} x rowgroup
// ---------------------------------------------------------------------------

template <int CTRL>
__device__ __forceinline__ float dpp_mov(float v) {
    return __int_as_float(__builtin_amdgcn_update_dpp(
        0, __float_as_int(v), CTRL, 0xf, 0xf, true));
}
__device__ __forceinline__ float wave_sum64(float v) {
    v += dpp_mov<0x111>(v);   // row_shr:1
    v += dpp_mov<0x112>(v);   // row_shr:2
    v += dpp_mov<0x114>(v);   // row_shr:4
    v += dpp_mov<0x118>(v);   // row_shr:8  -> lane15 of each 16-row = row sum
    v += dpp_mov<0x142>(v);   // row_bcast:15
    v += dpp_mov<0x143>(v);   // row_bcast:31 -> lane63 = total
    return v;                 // valid in lane 63 (identity 0 shifts in zeros)
}
__device__ __forceinline__ float wave_max64(float v) {
    v = fmaxf(v, dpp_mov<0x111>(v));
    v = fmaxf(v, dpp_mov<0x112>(v));
    v = fmaxf(v, dpp_mov<0x114>(v));
    v = fmaxf(v, dpp_mov<0x118>(v));
    v = fmaxf(v, dpp_mov<0x142>(v));
    v = fmaxf(v, dpp_mov<0x143>(v));
    return v;                 // valid in lane 63 (identity 0: inputs >= 0)
}

// Grid (BB, NW, 4): thread j builds a 16-bit partial of the 64-row bitmask
// word for its column, all 3 classes (u16 stores, little-endian, no atomics).
__global__ __launch_bounds__(WW) void buildbm(const int* __restrict__ targets,
                                              u16* __restrict__ bm16) {
    int b = blockIdx.x, w = blockIdx.y, q = blockIdx.z;
    int j = threadIdx.x;
    const int* tg = targets + (size_t)b * PLANE + (w * 64 + q * 16) * WW + j;
    unsigned m0 = 0, m1 = 0, m2 = 0;
#pragma unroll
    for (int r = 0; r < 16; ++r) {
        int t = tg[r * WW];
        unsigned bit = 1u << r;
        m0 |= (t == 0) ? bit : 0u;
        m1 |= (t == 1) ? bit : 0u;
        m2 |= (t == 2) ? bit : 0u;
    }
    size_t base = (((size_t)b * CC) * NW + w) * WW + j;          // c = 0
    bm16[base * 4 + q] = (u16)m0;
    bm16[(base + (size_t)NW * WW) * 4 + q] = (u16)m1;
    bm16[(base + 2 * (size_t)NW * WW) * 4 + q] = (u16)m2;
}

// Grid (GROUPS, BB): block = 4 rows x 384 cols, all 3 classes.
__global__ __launch_bounds__(WW) void edt4w(const u64* __restrict__ bm,
                                            const float* __restrict__ logits,
                                            float* __restrict__ out12) {
    __shared__ __align__(16) float g2s[ROWS_PG][CC][WW];   // 18432 B
    __shared__ float red[12][WW / 64];
    int g = blockIdx.x, b = blockIdx.y;
    int j = threadIdx.x;
    int i0 = g * ROWS_PG;
    int w = i0 >> 6;
    int wbase = w << 6;

    // ---- one deep batch of global loads: 18 bm words + 12 logits ----
    u64 wb0[NW], wb1[NW], wb2[NW];
#pragma unroll
    for (int wq = 0; wq < NW; ++wq) {
        wb0[wq] = bm[(((size_t)b * CC + 0) * NW + wq) * WW + j];
        wb1[wq] = bm[(((size_t)b * CC + 1) * NW + wq) * WW + j];
        wb2[wq] = bm[(((size_t)b * CC + 2) * NW + wq) * WW + j];
    }
    const float* lg = logits + ((size_t)b * CC * HH + i0) * WW + j;
    float lv[ROWS_PG][CC];
#pragma unroll
    for (int rl = 0; rl < ROWS_PG; ++rl) {
        lv[rl][0] = lg[rl * WW];
        lv[rl][1] = lg[PLANE + rl * WW];
        lv[rl][2] = lg[2 * PLANE + rl * WW];
    }

    // anchors: P = highest seed index in words < w, N = lowest in words > w
    u64 word[CC];
    int P[CC], N[CC];
#pragma unroll
    for (int c = 0; c < CC; ++c) {
        const u64* wbp = (c == 0) ? wb0 : (c == 1) ? wb1 : wb2;
        int p = -1, n = -1;
#pragma unroll
        for (int wq = 0; wq < NW; ++wq)
            if (wq < w && wbp[wq]) p = wq * 64 + 63 - __builtin_clzll(wbp[wq] | 1ull);
#pragma unroll
        for (int wq = NW - 1; wq >= 0; --wq)
            if (wq > w && wbp[wq]) n = wq * 64 + (int)__builtin_ctzll(wbp[wq] | 0x8000000000000000ull);
        P[c] = p; N[c] = n;
        word[c] = wbp[w];
    }

    // Phase A: 4 rows x 3 classes of exact column distances -> LDS.
    u64 lowmask = ((1ull << (i0 & 63)) << 1) - 1ull;    // bits 0..bi
#pragma unroll
    for (int rl = 0; rl < ROWS_PG; ++rl) {
        int i = i0 + rl;
        u64 himask = ~(lowmask >> 1);                   // bits bi..63
#pragma unroll
        for (int c = 0; c < CC; ++c) {
            u64 lo = word[c] & lowmask;
            int last = lo ? (wbase + 63 - __builtin_clzll(lo | 1ull)) : P[c];
            u64 hi = word[c] & himask;
            int next = hi ? (wbase + (int)__builtin_ctzll(hi | 0x8000000000000000ull)) : N[c];
            float fwd = (last >= 0) ? (float)(i - last) : (INF_F + (float)(i + 1));
            float bwd = (next >= 0) ? (float)(next - i) : (INF_F + (float)(HH - i));
            float gc = fminf(fwd, bwd);
            g2s[rl][c][j] = gc * gc;
        }
        lowmask = (lowmask << 1) | 1ull;
    }

    // softmax for all 4 rows pre-barrier (VALU overlaps LDS writes)
    float pr[ROWS_PG][CC];
#pragma unroll
    for (int rl = 0; rl < ROWS_PG; ++rl) {
        float l0 = lv[rl][0], l1 = lv[rl][1], l2 = lv[rl][2];
        float mx = fmaxf(l0, fmaxf(l1, l2));
        float x0 = __expf(l0 - mx), x1 = __expf(l1 - mx), x2 = __expf(l2 - mx);
        float rs = __fdividef(1.0f, x0 + x1 + x2);
        pr[rl][0] = x0 * rs; pr[rl][1] = x1 * rs; pr[rl][2] = x2 * rs;
    }
    __syncthreads();

    // aligned 12-float window covering [j-4, j+4]
    int basek = (j - 4) & ~3;
    if (basek < 0) basek = 0;
    if (basek > WW - 12) basek = WW - 12;
    float df0 = (float)(basek - j);

    // Phase B: window searches (two parallel min chains) + accumulation.
    float Sb0 = 0.f, Sb1 = 0.f, Sb2 = 0.f, Sf0 = 0.f, Sf1 = 0.f, Sf2 = 0.f;
    float Mb0 = 0.f, Mb1 = 0.f, Mb2 = 0.f, Mf0 = 0.f, Mf1 = 0.f, Mf2 = 0.f;
#pragma unroll
    for (int rl = 0; rl < ROWS_PG; ++rl) {
        int bi = (i0 + rl) & 63;
        float d[CC];
#pragma unroll
        for (int c = 0; c < CC; ++c) {
            const float* g2 = g2s[rl][c];
            // 3 independent b128 loads — one latency wait, no chain
            float4 W0 = *(const float4*)(g2 + basek);
            float4 W1 = *(const float4*)(g2 + basek + 4);
            float4 W2 = *(const float4*)(g2 + basek + 8);
            float d0 = df0,       d1 = df0 + 1.f;
            float d2 = df0 + 2.f, d3 = df0 + 3.f;
            // chain A: elements 0,2,4,6,8,10 ; chain B: 1,3,5,7,9,11
            float mA =            fmaf(d0, d0, W0.x);
            float mB =            fmaf(d1, d1, W0.y);
            mA = fminf(mA, fmaf(d2, d2, W0.z));
            mB = fminf(mB, fmaf(d3, d3, W0.w));
            d0 += 4.f; d1 += 4.f; d2 += 4.f; d3 += 4.f;
            mA = fminf(mA, fmaf(d0, d0, W1.x));
            mB = fminf(mB, fmaf(d1, d1, W1.y));
            mA = fminf(mA, fmaf(d2, d2, W1.z));
            mB = fminf(mB, fmaf(d3, d3, W1.w));
            d0 += 4.f; d1 += 4.f; d2 += 4.f; d3 += 4.f;
            mA = fminf(mA, fmaf(d0, d0, W2.x));
            mB = fminf(mB, fmaf(d1, d1, W2.y));
            mA = fminf(mA, fmaf(d2, d2, W2.z));
            mB = fminf(mB, fmaf(d3, d3, W2.w));
            float mn = fminf(mA, mB);
            if (__builtin_expect(mn > 25.f, 0)) {   // radius-4 prune failed
                for (int r0 = 5; r0 < WW; r0 += CHUNK) {
                    float r0sq = (float)(r0 * r0);  // exact fp32 integer
                    if (r0sq >= mn) break;
                    float cl[CHUNK], cr[CHUNK];
#pragma unroll
                    for (int u = 0; u < CHUNK; ++u) {
                        int r = r0 + u;
                        int kl = j - r; kl = (kl < 0) ? 0 : kl;
                        int kr = j + r; kr = (kr > WW - 1) ? WW - 1 : kr;
                        cl[u] = g2[kl];
                        cr[u] = g2[kr];
                    }
#pragma unroll
                    for (int u = 0; u < CHUNK; ++u) {
                        float rr = (float)((r0 + u) * (r0 + u));
                        mn = fminf(mn, fminf(rr + cl[u], rr + cr[u]));
                    }
                }
            }
            d[c] = sqrtf(mn);
        }
        // fg_c = (t==c) ? min of other two bg dists : 0
        float f0 = ((word[0] >> bi) & 1ull) ? fminf(d[1], d[2]) : 0.f;
        float f1 = ((word[1] >> bi) & 1ull) ? fminf(d[0], d[2]) : 0.f;
        float f2 = ((word[2] >> bi) & 1ull) ? fminf(d[0], d[1]) : 0.f;

        Sb0 += pr[rl][0] * d[0]; Sb1 += pr[rl][1] * d[1]; Sb2 += pr[rl][2] * d[2];
        Sf0 += pr[rl][0] * f0;   Sf1 += pr[rl][1] * f1;   Sf2 += pr[rl][2] * f2;
        Mb0 = fmaxf(Mb0, d[0]); Mb1 = fmaxf(Mb1, d[1]); Mb2 = fmaxf(Mb2, d[2]);
        Mf0 = fmaxf(Mf0, f0);   Mf1 = fmaxf(Mf1, f1);   Mf2 = fmaxf(Mf2, f2);
    }

    // DPP wave reduction (VALU pipe) -> lane 63; then tiny cross-wave combine.
    float acc[12] = {Sb0, Sf0, Mb0, Mf0, Sb1, Sf1, Mb1, Mf1, Sb2, Sf2, Mb2, Mf2};
    int lane = j & 63, wid = j >> 6;
#pragma unroll
    for (int a = 0; a < 12; ++a) {
        bool ismax = (a & 2) != 0;         // k = a&3: 0,1 sums; 2,3 maxes
        float v = ismax ? wave_max64(acc[a]) : wave_sum64(acc[a]);
        if (lane == 63) red[a][wid] = v;
    }
    __syncthreads();
    if (j < 12) {
        int c = j >> 2, k = j & 3;
        bool ismax = (k & 2) != 0;
        float v = red[j][0];
#pragma unroll
        for (int t = 1; t < WW / 64; ++t)
            v = ismax ? fmaxf(v, red[j][t]) : (v + red[j][t]);
        out12[((size_t)(b * CC + c) * 4 + k) * GROUPS + g] = v;
    }
}

// One block: reduce 24 masks x 4 stats x 96 groups -> scalar loss.
__global__ __launch_bounds__(WW) void final_k(const float* __restrict__ out12,
                                              float* __restrict__ out) {
    __shared__ float contrib[NMASK];
    int t = threadIdx.x;
    int m = t >> 4, l = t & 15;            // 24 masks x 16 lanes
    float sb = 0.f, sf = 0.f, mb = 0.f, mf = 0.f;
    for (int gg = l; gg < GROUPS; gg += 16) {
        const float* p = out12 + (size_t)m * 4 * GROUPS + gg;
        sb += p[0 * GROUPS];
        sf += p[1 * GROUPS];
        mb = fmaxf(mb, p[2 * GROUPS]);
        mf = fmaxf(mf, p[3 * GROUPS]);
    }
#pragma unroll
    for (int off = 8; off > 0; off >>= 1) {
        sb += __shfl_down(sb, off, 16);
        sf += __shfl_down(sf, off, 16);
        mb = fmaxf(mb, __shfl_down(mb, off, 16));
        mf = fmaxf(mf, __shfl_down(mf, off, 16));
    }
    if (l == 0) {
        float cv = 0.f;
        if (mb <= 1000.0f)                 // mask non-empty
            cv = sb / fmaxf(mb, 1e-12f) - sf / fmaxf(mf, 1e-12f);
        contrib[m] = cv;
    }
    __syncthreads();
    if (t == 0) {
        float tot = 0.f;
        for (int mk = 0; mk < NMASK; ++mk) tot += contrib[mk];
        out[0] = tot / (float)((size_t)BB * CC * PLANE);
    }
}

extern "C" void kernel_launch(void* const* d_in, const int* in_sizes, int n_in,
                              void* d_out, int out_size, void* d_ws, size_t ws_size,
                              hipStream_t stream) {
    const float* logits = (const float*)d_in[0];   // [8,3,384,384] f32
    const int* targets = (const int*)d_in[1];      // [8,384,384] i32
    float* out = (float*)d_out;                    // scalar f32

    u64* bm = (u64*)d_ws;                                       // 55296 u64
    float* out12 = (float*)(bm + (size_t)BB * CC * NW * WW);    // 9216 floats

    {
        dim3 grid(BB, NW, 4);                                   // 192 blocks
        buildbm<<<grid, WW, 0, stream>>>(targets, (u16*)bm);
    }
    {
        dim3 grid(GROUPS, BB);                                  // 96*8 = 768 blocks
        edt4w<<<grid, WW, 0, stream>>>(bm, logits, out12);
    }
    final_k<<<1, WW, 0, stream>>>(out12, out);
}